// Round 1
// baseline (82.626 us; speedup 1.0000x reference)
//
#include <hip/hip_runtime.h>

#define BB 16
#define CC 256
#define TT 512

// Phase 1: per-batch inclusive scan of durations + scatter of frame->phoneme idx.
__global__ __launch_bounds__(TT) void lr_scan_kernel(
    const int* __restrict__ dur,      // [B, T]
    int* __restrict__ ws_mel,         // [B]
    int* __restrict__ ws_idx,         // [B, L]
    float* __restrict__ out_mel,      // d_out + B*C*L, [B]
    int L)
{
    __shared__ int s[TT];
    const int b = blockIdx.x;
    const int t = threadIdx.x;

    int d = dur[b * TT + t];
    if (d < 0) d = 0;
    s[t] = d;
    __syncthreads();

    // Hillis-Steele inclusive scan over T=512
    #pragma unroll
    for (int off = 1; off < TT; off <<= 1) {
        int v = (t >= off) ? s[t - off] : 0;
        __syncthreads();
        s[t] += v;
        __syncthreads();
    }

    const int cum = s[t];          // inclusive cumsum
    const int start = cum - d;

    int* idx = ws_idx + (size_t)b * L;
    for (int f = start; f < cum; ++f) idx[f] = t;

    if (t == TT - 1) {
        ws_mel[b] = cum;
        out_mel[b] = (float)cum;   // mel_len emitted as float (harness reads float32)
    }
}

// Phase 2: gather + zero-fill padding.
__global__ __launch_bounds__(256) void lr_gather_kernel(
    const float* __restrict__ x,      // [B, C, T]
    const int* __restrict__ ws_mel,   // [B]
    const int* __restrict__ ws_idx,   // [B, L]
    float* __restrict__ out,          // [B, C, L]
    int L)
{
    const int f = blockIdx.x * 256 + threadIdx.x;
    const int c = blockIdx.y;
    const int b = blockIdx.z;
    if (f >= L) return;

    const int ml = ws_mel[b];
    float v = 0.0f;
    if (f < ml) {
        const int idx = ws_idx[(size_t)b * L + f];
        v = x[((size_t)b * CC + c) * TT + idx];
    }
    out[((size_t)b * CC + c) * (size_t)L + f] = v;
}

extern "C" void kernel_launch(void* const* d_in, const int* in_sizes, int n_in,
                              void* d_out, int out_size, void* d_ws, size_t ws_size,
                              hipStream_t stream)
{
    const float* x  = (const float*)d_in[0];
    const int* dur  = (const int*)d_in[1];
    float* out      = (float*)d_out;

    // out = [B, C, L] floats ++ mel_len[B]  =>  L = (out_size - B) / (B*C)
    const int L = (out_size - BB) / (BB * CC);

    int* ws_mel = (int*)d_ws;        // B ints
    int* ws_idx = ws_mel + BB;       // B*L ints
    float* out_mel = out + (size_t)BB * CC * L;

    lr_scan_kernel<<<BB, TT, 0, stream>>>(dur, ws_mel, ws_idx, out_mel, L);

    dim3 grid((L + 255) / 256, CC, BB);
    lr_gather_kernel<<<grid, 256, 0, stream>>>(x, ws_mel, ws_idx, out, L);
}